// Round 13
// baseline (1945.436 us; speedup 1.0000x reference)
//
#include <hip/hip_runtime.h>
#include <math.h>

// 3-layer LSTM (H=64, T=512, B=2048, Din=16), R13: gts eliminated.
// R12 post-mortem: LDS-issue-bound; gts round-trip + 2 barriers/iter was the
// largest removable term (R12's [b][u][4] relayout also added 4-way write
// conflicts: 8.4M -> 25.7M conflict cycles).
// R13: remap B-cols so each 4-lane QUAD holds all 4 gates of one u:
//   ncol = (c&3)*64 + wid*4 + (c>>2)   (gate index on lane bits 0-1)
// After the h-MFMA, a 4x4 gate<->batch transpose runs entirely in VALU via
// DPP quad_perm (8 mov_dpp + 8 cndmask); each active lane computes its own
// cell in-register. c-state migrates between parity half-waves with one
// __shfl_xor(cst,32). h plane double-buffered -> ONE barrier per iteration.
// Staging runs on the inactive half-wave lanes. All global addresses are
// identical to R11/R12 (determinism); arithmetic is bit-identical to R12
// (absmax should reproduce ~9.77e-4).

#define T_STEPS 512
#define BATCH   2048
#define HID     64
#define CB      8
#define NTHR    1024
#define SEQS    (BATCH * HID)     // hseq u32 elements per timestep

typedef __attribute__((ext_vector_type(8))) _Float16 f16x8;
typedef __attribute__((ext_vector_type(4))) float f32x4;

__device__ __forceinline__ float sigm(float z) { return 1.0f / (1.0f + __expf(-z)); }
__device__ __forceinline__ float tanh_f(float z) {
    z = fminf(15.0f, fmaxf(-15.0f, z));
    const float e = __expf(2.0f * z);
    return (e - 1.0f) / (e + 1.0f);
}
// truncate f32 -> bf16 (lo term captures the remainder)
__device__ __forceinline__ short tb(float v) { return (short)(__float_as_uint(v) >> 16); }
__device__ __forceinline__ float fb(unsigned h) {
    return __uint_as_float((h & 0xffffu) << 16);
}
// 8-row 128B/row fp16 plane, XOR-swizzled 16B units; rows alias &7
__device__ __forceinline__ int ha(int row, int u8) {
    row &= 7;
    return row * 128 + ((u8 ^ row) << 4);
}
__device__ __forceinline__ void hwr16(_Float16* p, int row, int u, _Float16 v) {
    *(_Float16*)((char*)p + ha(row, u >> 3) + (u & 7) * 2) = v;
}
__device__ __forceinline__ f16x8 hrd16(const _Float16* p, int row, int u8) {
    return *(const f16x8*)((const char*)p + ha(row, u8));
}
// 16-row fp16 x plane (pair-step even in rows 0-7, odd in 8-15), XOR on row&7
__device__ __forceinline__ int xaddr(int row, int u8) {
    return row * 128 + ((u8 ^ (row & 7)) << 4);
}
__device__ __forceinline__ void xwr16(_Float16* p, int row, int k, _Float16 v) {
    *(_Float16*)((char*)p + xaddr(row, k >> 3) + (k & 7) * 2) = v;
}
__device__ __forceinline__ f16x8 xrd16(const _Float16* p, int row, int u8) {
    return *(const f16x8*)((const char*)p + xaddr(row, u8));
}
// DPP quad_perm lane permute (VALU pipe, no LDS)
template<int CTRL>
__device__ __forceinline__ float qp(float v) {
    return __int_as_float(__builtin_amdgcn_mov_dpp(__float_as_int(v), CTRL, 0xf, 0xf, true));
}

#define MFMA16(A, B, C)  __builtin_amdgcn_mfma_f32_16x16x32_f16((A), (B), (C), 0, 0, 0)

// x-side pass over fp16 plane buffer NB -> DST (2 timesteps; bias folded in)
#define X_PASS(DST, NB) do {                                                  \
    DST[0] = biasr; DST[1] = biasr; DST[2] = biasr; DST[3] = biasr;           \
    {                                                                         \
        const f16x8 ax0 = xrd16(&xp[NB][0], arow, 0 + ksub);                  \
        DST = MFMA16(ax0, WIh0, DST);                                         \
    }                                                                         \
    if (Din > 32) {                                                           \
        const f16x8 ax1 = xrd16(&xp[NB][0], arow, 4 + ksub);                  \
        DST = MFMA16(ax1, WIh1, DST);                                         \
    }                                                                         \
} while (0)

__global__ __launch_bounds__(NTHR) void lstm_layer(
    const float* __restrict__ x0,    // layer0 input [B][T][16] fp32, or null
    unsigned*    __restrict__ hseq,  // [T][B][64] packed bf16 hi|lo<<16
    const float* __restrict__ Wih,   // [256][Din]
    const float* __restrict__ Whh,   // [256][64]
    const float* __restrict__ bih,   // [256]
    const float* __restrict__ bhh,   // [256]
    const float* __restrict__ Wout,  // [7][64] (head only)
    const float* __restrict__ bout,  // [7]
    float* __restrict__ out,         // [B][7]
    int Din, int store_h, int do_head)
{
    __shared__ __attribute__((aligned(16))) _Float16 xp[2][16 * 64];
    __shared__ __attribute__((aligned(16))) _Float16 hp[2][8 * 64];
    __shared__ __attribute__((aligned(16))) float hf[8 * HID];

    const int tid  = threadIdx.x;
    const int lane = tid & 63;
    const int wid  = tid >> 6;          // 0..15
    const int c    = lane & 15;         // B-fragment column within tile
    const int ncol = (c & 3) * 64 + wid * 4 + (c >> 2);  // gate row in [0,256)
    const int ksub = (lane >> 4) & 3;   // k-subgroup of 8
    const int arow = lane & 15;         // A row (hardware-fixed)
    const int bloc = ((lane >> 4) & 1) * 4 + (c & 3);    // this lane's batch
    const int uloc = wid * 4 + (c >> 2);                 // this lane's unit
    const int b0   = blockIdx.x * CB;

    // ---- weight fragments: 1-term fp16, resident for the whole kernel ----
    f16x8 WIh0 = {0,0,0,0,0,0,0,0}, WIh1 = {0,0,0,0,0,0,0,0};
    f16x8 WHh0, WHh1;
    {
        const int k0 = ksub * 8;
        if (k0 < Din) {
            const float4 a = *(const float4*)(Wih + ncol * Din + k0);
            const float4 b = *(const float4*)(Wih + ncol * Din + k0 + 4);
            f16x8 w;
            w[0]=(_Float16)a.x; w[1]=(_Float16)a.y; w[2]=(_Float16)a.z; w[3]=(_Float16)a.w;
            w[4]=(_Float16)b.x; w[5]=(_Float16)b.y; w[6]=(_Float16)b.z; w[7]=(_Float16)b.w;
            WIh0 = w;
        }
        if (Din > 32) {
            const float4 a = *(const float4*)(Wih + ncol * Din + 32 + k0);
            const float4 b = *(const float4*)(Wih + ncol * Din + 32 + k0 + 4);
            f16x8 w;
            w[0]=(_Float16)a.x; w[1]=(_Float16)a.y; w[2]=(_Float16)a.z; w[3]=(_Float16)a.w;
            w[4]=(_Float16)b.x; w[5]=(_Float16)b.y; w[6]=(_Float16)b.z; w[7]=(_Float16)b.w;
            WIh1 = w;
        }
    }
    {
        const int k0 = ksub * 8;
        const float4 a = *(const float4*)(Whh + ncol * HID + k0);
        const float4 b = *(const float4*)(Whh + ncol * HID + k0 + 4);
        const float4 cc = *(const float4*)(Whh + ncol * HID + 32 + k0);
        const float4 d = *(const float4*)(Whh + ncol * HID + 32 + k0 + 4);
        f16x8 w0, w1;
        w0[0]=(_Float16)a.x; w0[1]=(_Float16)a.y; w0[2]=(_Float16)a.z; w0[3]=(_Float16)a.w;
        w0[4]=(_Float16)b.x; w0[5]=(_Float16)b.y; w0[6]=(_Float16)b.z; w0[7]=(_Float16)b.w;
        w1[0]=(_Float16)cc.x; w1[1]=(_Float16)cc.y; w1[2]=(_Float16)cc.z; w1[3]=(_Float16)cc.w;
        w1[4]=(_Float16)d.x; w1[5]=(_Float16)d.y; w1[6]=(_Float16)d.z; w1[7]=(_Float16)d.w;
        WHh0 = w0; WHh1 = w1;
    }
    const float biasr = bih[ncol] + bhh[ncol];

    // ---- zero planes ----
    ((unsigned*)xp)[tid] = 0;                       // 1024 u32 = both x bufs
    if (tid < 512) ((unsigned*)hp)[tid] = 0;        // both h bufs
    __syncthreads();

    // ---- prologue: stage steps 0..3 (pairs {0,1}->buf0, {2,3}->buf1) ----
    if (tid >= 512) {
        const int t2 = tid - 512;
        if (x0) {
            if (t2 < 128) {
                const int b = t2 >> 4, k = t2 & 15;
                #pragma unroll
                for (int s = 0; s < 4; ++s) {
                    const float v = x0[(size_t)(b0 + b) * (T_STEPS * 16) + s * 16 + k];
                    xwr16(&xp[(s >> 1) & 1][0], ((s & 1) << 3) + b, k, (_Float16)v);
                }
            }
        } else {
            const int b = t2 >> 6, u = t2 & 63;
            #pragma unroll
            for (int s = 0; s < 4; ++s) {
                const unsigned p = hseq[(size_t)s * SEQS + (b0 + b) * HID + u];
                const float v = fb(p) + fb(p >> 16);
                xwr16(&xp[(s >> 1) & 1][0], ((s & 1) << 3) + b, u, (_Float16)v);
            }
        }
    }
    __syncthreads();

    // ---- prologue: x contribution (+bias) for pair {0,1} ----
    f32x4 CxCur; X_PASS(CxCur, 0);
    f32x4 CxNext = {0.f, 0.f, 0.f, 0.f};

    float cst = 0.0f;

    // running pointers (per-lane (bloc,uloc) cell/staging addresses)
    const unsigned* hin = hseq + (size_t)4 * SEQS + (size_t)(b0 + bloc) * HID + uloc;
    const float* xin = x0 ? x0 + (size_t)(b0 + bloc) * (T_STEPS * 16) + 4 * 16 + uloc
                          : nullptr;
    unsigned* hout = hseq + (size_t)(b0 + bloc) * HID + uloc;

    for (int t = 0; t < T_STEPS; ++t) {
        const bool act = ((lane >> 5) == (t & 1));

        // ---- staging prefetch issue (inactive half-wave lanes) ----
        float pxn = 0.0f; unsigned phn = 0;
        if (!act && t + 4 < T_STEPS) {
            if (x0) {
                if (wid < 4) pxn = *xin;
            } else {
                phn = *hin;
            }
        }

        // ---- h-side MFMA folded onto Cx (reads h(t-1) buffer) ----
        f32x4 G;
        {
            const f16x8 ah0 = hrd16(&hp[(t + 1) & 1][0], arow, ksub);
            const f16x8 ah1 = hrd16(&hp[(t + 1) & 1][0], arow, 4 + ksub);
            G = MFMA16(ah0, WHh0, CxCur);
            G = MFMA16(ah1, WHh1, G);
        }

        // ---- (even t) x-pass for pair {t+2,t+3} ----
        if ((t & 1) == 0 && t + 2 < T_STEPS) {
            X_PASS(CxNext, ((t >> 1) + 1) & 1);
        }

        if (act) {
            // ---- 4x4 gate<->batch transpose within quads (pure VALU) ----
            // quad lane p holds M[p][j] = (gate p, batch j); want M[j][p].
            const int p0 = c & 1, p1 = (c >> 1) & 1;
            const float q0 = qp<0xB1>(G[0]), q1 = qp<0xB1>(G[1]);
            const float q2 = qp<0xB1>(G[2]), q3 = qp<0xB1>(G[3]);
            const float t0 = p0 ? q1 : G[0];
            const float t1 = p0 ? G[1] : q0;
            const float t2 = p0 ? q3 : G[2];
            const float t3 = p0 ? G[3] : q2;
            const float s0 = qp<0x4E>(t0), s1 = qp<0x4E>(t1);
            const float s2 = qp<0x4E>(t2), s3 = qp<0x4E>(t3);
            const float gi = p1 ? s2 : t0;
            const float gf = p1 ? s3 : t1;
            const float gg = p1 ? t2 : s0;
            const float go = p1 ? t3 : s1;
            // ---- cell (fp32 state) ----
            cst = sigm(gf) * cst + sigm(gi) * tanh_f(gg);
            const float h = sigm(go) * tanh_f(cst);
            hwr16(&hp[t & 1][0], bloc, uloc, (_Float16)h);
            if (store_h) {
                const short hh = tb(h);
                const short hl = tb(h - fb((unsigned)(unsigned short)hh));
                *hout = (unsigned)(unsigned short)hh |
                        ((unsigned)(unsigned short)hl << 16);
            }
            if (do_head && t == T_STEPS - 1) hf[bloc * HID + uloc] = h;
        } else if (t + 4 < T_STEPS) {
            // ---- staging plane write for step t+4 ----
            const int row = ((t & 1) << 3) + bloc;
            if (x0) {
                if (wid < 4) xwr16(&xp[(t >> 1) & 1][0], row, uloc, (_Float16)pxn);
            } else {
                xwr16(&xp[(t >> 1) & 1][0], row, uloc,
                      (_Float16)(fb(phn) + fb(phn >> 16)));
            }
        }

        // migrate c-state to the half-wave that is active next iteration
        cst = __shfl_xor(cst, 32, 64);
        __syncthreads();

        if (t & 1) CxCur = CxNext;   // pair hand-off (wave-uniform)
        hin += SEQS;
        hout += SEQS;
        if (x0) xin += 16;
    }

    // ---- head: out = h2[T-1] @ Wout^T + bout ----
    if (do_head && tid < 7 * CB) {
        const int b = tid / 7, o = tid % 7;
        float a = bout[o];
        #pragma unroll
        for (int k = 0; k < HID; ++k)
            a = fmaf(hf[b * HID + k], Wout[o * HID + k], a);
        out[(b0 + b) * 7 + o] = a;
    }
}

extern "C" void kernel_launch(void* const* d_in, const int* in_sizes, int n_in,
                              void* d_out, int out_size, void* d_ws, size_t ws_size,
                              hipStream_t stream) {
    const float* x    = (const float*)d_in[0];
    const float* Wih0 = (const float*)d_in[1];
    const float* Whh0 = (const float*)d_in[2];
    const float* bih0 = (const float*)d_in[3];
    const float* bhh0 = (const float*)d_in[4];
    const float* Wih1 = (const float*)d_in[5];
    const float* Whh1 = (const float*)d_in[6];
    const float* bih1 = (const float*)d_in[7];
    const float* bhh1 = (const float*)d_in[8];
    const float* Wih2 = (const float*)d_in[9];
    const float* Whh2 = (const float*)d_in[10];
    const float* bih2 = (const float*)d_in[11];
    const float* bhh2 = (const float*)d_in[12];
    const float* Wout = (const float*)d_in[13];
    const float* bout = (const float*)d_in[14];
    float* out = (float*)d_out;
    unsigned* hseq = (unsigned*)d_ws;   // needs T*B*64*4 = 268,435,456 B

    const dim3 grid(BATCH / CB), blk(NTHR);
    lstm_layer<<<grid, blk, 0, stream>>>(x, hseq, Wih0, Whh0, bih0, bhh0,
                                         nullptr, nullptr, nullptr, 16, 1, 0);
    lstm_layer<<<grid, blk, 0, stream>>>(nullptr, hseq, Wih1, Whh1, bih1, bhh1,
                                         nullptr, nullptr, nullptr, HID, 1, 0);
    lstm_layer<<<grid, blk, 0, stream>>>(nullptr, hseq, Wih2, Whh2, bih2, bhh2,
                                         Wout, bout, out, HID, 0, 1);
}

// Round 14
// 1317.634 us; speedup vs baseline: 1.4765x; 1.4765x over previous
//
#include <hip/hip_runtime.h>
#include <math.h>

// 3-layer LSTM (H=64, T=512, B=2048, Din=16), R14: 2 blocks/CU latency overlap.
// R13 lesson: specialize by WAVE, not half-wave (half-wave split serialized
// exec-mask halves -> +50%). R14 returns to R11/R12's wave-specialized loop
// and attacks the ~800 cyc/iter barrier-latency residual with co-residency:
//   512-thread blocks, CB=4, grid=512 -> 2 blocks/CU; one block's MFMA phase
//   overlaps the other's barrier drain.
// Per block: 8 waves; each wave owns TWO 16-col tiles (A-frags shared).
// The 16 A-rows pack FOUR timesteps of x (rows 4s+b) -> x-pass once per 4
// iters. Cell = waves 0-3 (256 cells), staging = waves 4-7 (t+8 window).
// Numerics identical to R12/R13: fp16 1-term weights + fp16 planes, fp32
// cell state, hseq u32 bf16 hi|lo (absmax should reproduce ~9.77e-4).

#define T_STEPS 512
#define BATCH   2048
#define HID     64
#define CB      4
#define NTHR    512
#define SEQS    (BATCH * HID)     // hseq u32 elements per timestep

typedef __attribute__((ext_vector_type(8))) _Float16 f16x8;
typedef __attribute__((ext_vector_type(4))) float f32x4;

__device__ __forceinline__ float sigm(float z) { return 1.0f / (1.0f + __expf(-z)); }
__device__ __forceinline__ float tanh_f(float z) {
    z = fminf(15.0f, fmaxf(-15.0f, z));
    const float e = __expf(2.0f * z);
    return (e - 1.0f) / (e + 1.0f);
}
__device__ __forceinline__ short tb(float v) { return (short)(__float_as_uint(v) >> 16); }
__device__ __forceinline__ float fb(unsigned h) {
    return __uint_as_float((h & 0xffffu) << 16);
}
// 4-row fp16 h plane (rows alias &3), XOR-swizzled 16B units
__device__ __forceinline__ int ha(int row, int u8) {
    row &= 3;
    return row * 128 + ((u8 ^ row) << 4);
}
__device__ __forceinline__ void hwr16(_Float16* p, int row, int u, _Float16 v) {
    *(_Float16*)((char*)p + ha(row, u >> 3) + (u & 7) * 2) = v;
}
__device__ __forceinline__ f16x8 hrd16(const _Float16* p, int row, int u8) {
    return *(const f16x8*)((const char*)p + ha(row, u8));
}
// 16-row fp16 x plane: row = 4*stepslot + batch; XOR on row&7
__device__ __forceinline__ int xaddr(int row, int u8) {
    return row * 128 + ((u8 ^ (row & 7)) << 4);
}
__device__ __forceinline__ void xwr16(_Float16* p, int row, int k, _Float16 v) {
    *(_Float16*)((char*)p + xaddr(row, k >> 3) + (k & 7) * 2) = v;
}
__device__ __forceinline__ f16x8 xrd16(const _Float16* p, int row, int u8) {
    return *(const f16x8*)((const char*)p + xaddr(row, u8));
}

#define MFMA16(A, B, C)  __builtin_amdgcn_mfma_f32_16x16x32_f16((A), (B), (C), 0, 0, 0)

// x-side pass over plane buffer NB -> both tiles (covers 4 timesteps)
#define X_PASS(DA, DB, NB) do {                                               \
    DA[0] = biasA; DA[1] = biasA; DA[2] = biasA; DA[3] = biasA;               \
    DB[0] = biasB; DB[1] = biasB; DB[2] = biasB; DB[3] = biasB;               \
    {                                                                         \
        const f16x8 ax0 = xrd16(&xp[NB][0], arow, 0 + ksub);                  \
        DA = MFMA16(ax0, WIA0, DA);                                           \
        DB = MFMA16(ax0, WIB0, DB);                                           \
    }                                                                         \
    if (Din > 32) {                                                           \
        const f16x8 ax1 = xrd16(&xp[NB][0], arow, 4 + ksub);                  \
        DA = MFMA16(ax1, WIA1, DA);                                           \
        DB = MFMA16(ax1, WIB1, DB);                                           \
    }                                                                         \
} while (0)

__device__ __forceinline__ f16x8 ldw16(const float* p) {
    const float4 a = *(const float4*)p;
    const float4 b = *(const float4*)(p + 4);
    f16x8 w;
    w[0]=(_Float16)a.x; w[1]=(_Float16)a.y; w[2]=(_Float16)a.z; w[3]=(_Float16)a.w;
    w[4]=(_Float16)b.x; w[5]=(_Float16)b.y; w[6]=(_Float16)b.z; w[7]=(_Float16)b.w;
    return w;
}

__global__
__attribute__((amdgpu_flat_work_group_size(NTHR, NTHR),
               amdgpu_waves_per_eu(4, 4)))
void lstm_layer(
    const float* __restrict__ x0,    // layer0 input [B][T][16] fp32, or null
    unsigned*    __restrict__ hseq,  // [T][B][64] packed bf16 hi|lo<<16
    const float* __restrict__ Wih,   // [256][Din]
    const float* __restrict__ Whh,   // [256][64]
    const float* __restrict__ bih,   // [256]
    const float* __restrict__ bhh,   // [256]
    const float* __restrict__ Wout,  // [7][64] (head only)
    const float* __restrict__ bout,  // [7]
    float* __restrict__ out,         // [B][7]
    int Din, int store_h, int do_head)
{
    __shared__ __attribute__((aligned(16))) _Float16 xp[2][16 * 64];
    __shared__ __attribute__((aligned(16))) _Float16 hp[4 * 64];
    __shared__ __attribute__((aligned(16))) float gts[4 * 256];  // [b][gaterow]
    __shared__ __attribute__((aligned(16))) float hf[4 * HID];

    const int tid  = threadIdx.x;
    const int lane = tid & 63;
    const int wid  = tid >> 6;            // 0..7
    const int ncolA = wid * 32 + (lane & 15);
    const int ncolB = ncolA + 16;
    const int ksub = (lane >> 4) & 3;
    const int arow = lane & 15;
    const int b0   = blockIdx.x * CB;
    const int t2m  = tid & 255;           // staging-local index (valid tid>=256)

    // ---- weight fragments: 1-term fp16, two tiles per wave ----
    f16x8 WIA0 = {0,0,0,0,0,0,0,0}, WIA1 = {0,0,0,0,0,0,0,0};
    f16x8 WIB0 = {0,0,0,0,0,0,0,0}, WIB1 = {0,0,0,0,0,0,0,0};
    f16x8 WHA0, WHA1, WHB0, WHB1;
    {
        const int k0 = ksub * 8;
        if (k0 < Din) {
            WIA0 = ldw16(Wih + ncolA * Din + k0);
            WIB0 = ldw16(Wih + ncolB * Din + k0);
        }
        if (Din > 32) {
            WIA1 = ldw16(Wih + ncolA * Din + 32 + k0);
            WIB1 = ldw16(Wih + ncolB * Din + 32 + k0);
        }
        WHA0 = ldw16(Whh + ncolA * HID + k0);
        WHA1 = ldw16(Whh + ncolA * HID + 32 + k0);
        WHB0 = ldw16(Whh + ncolB * HID + k0);
        WHB1 = ldw16(Whh + ncolB * HID + 32 + k0);
    }
    const float biasA = bih[ncolA] + bhh[ncolA];
    const float biasB = bih[ncolB] + bhh[ncolB];

    // ---- zero planes ----
    ((unsigned*)xp)[tid] = 0; ((unsigned*)xp)[tid + 512] = 0;  // 1024 u32
    if (tid < 128) ((unsigned*)hp)[tid] = 0;                   // 4*64 fp16
    __syncthreads();

    // ---- prologue: stage steps 0..7 (groups 0 -> buf0, 1 -> buf1) ----
    if (tid >= 256) {
        if (x0) {
            if (t2m < 64) {
                const int b = t2m >> 4, k = t2m & 15;
                #pragma unroll
                for (int s8 = 0; s8 < 8; ++s8) {
                    const float v = x0[(size_t)(b0 + b) * (T_STEPS * 16) + s8 * 16 + k];
                    xwr16(&xp[s8 >> 2][0], (s8 & 3) * 4 + b, k, (_Float16)v);
                }
            }
        } else {
            const int b = t2m >> 6, u = t2m & 63;
            #pragma unroll
            for (int s8 = 0; s8 < 8; ++s8) {
                const unsigned p = hseq[(size_t)s8 * SEQS + (b0 + b) * HID + u];
                xwr16(&xp[s8 >> 2][0], (s8 & 3) * 4 + b, u,
                      (_Float16)(fb(p) + fb(p >> 16)));
            }
        }
    }
    __syncthreads();

    // ---- prologue: x contribution (+bias) for group 0 ----
    f32x4 CxA, CxB, CxnA = {0,0,0,0}, CxnB = {0,0,0,0};
    X_PASS(CxA, CxB, 0);

    float cst = 0.0f;   // c state (threads < 256: one (b,u) cell each)

    // running pointers
    const unsigned* hin = hseq + (size_t)8 * SEQS +
                          (size_t)(b0 + (t2m >> 6)) * HID + (t2m & 63);
    const float* xin = x0 ? x0 + (size_t)(b0 + ((t2m & 63) >> 4)) * (T_STEPS * 16) +
                             8 * 16 + (t2m & 15)
                          : nullptr;
    unsigned* hout = hseq + (size_t)(b0 + (t2m >> 6)) * HID + (t2m & 63);

    for (int t = 0; t < T_STEPS; ++t) {
        const int s = t & 3, g = t >> 2;

        // ---- staging prefetch issue (waves 4-7) ----
        float pxn = 0.0f; unsigned phn = 0;
        if (tid >= 256 && t + 8 < T_STEPS) {
            if (x0) {
                if (t2m < 64) pxn = *xin;
            } else {
                phn = *hin;
            }
        }

        // ---- h-side MFMA, both tiles, folded onto Cx ----
        f32x4 GA, GB;
        {
            const f16x8 ah0 = hrd16(hp, arow, ksub);
            const f16x8 ah1 = hrd16(hp, arow, 4 + ksub);
            GA = MFMA16(ah0, WHA0, CxA);
            GB = MFMA16(ah0, WHB0, CxB);
            GA = MFMA16(ah1, WHA1, GA);
            GB = MFMA16(ah1, WHB1, GB);
        }

        // ---- (group start) x-pass for next group ----
        if (s == 0 && t + 4 < T_STEPS) {
            X_PASS(CxnA, CxnB, (g + 1) & 1);
        }

        // ---- gts write: quarter holding step t's rows (4s..4s+3) ----
        if ((lane >> 4) == s) {
            #pragma unroll
            for (int j = 0; j < 4; ++j) {
                gts[j * 256 + ncolA] = GA[j];
                gts[j * 256 + ncolB] = GB[j];
            }
        }
        __syncthreads();

        // ---- cell (waves 0-3) || staging plane write (waves 4-7) ----
        if (tid < 256) {
            const int b = tid >> 6, u = tid & 63;
            const float gi = gts[b * 256 + u];
            const float gf = gts[b * 256 + 64 + u];
            const float gg = gts[b * 256 + 128 + u];
            const float go = gts[b * 256 + 192 + u];
            cst = sigm(gf) * cst + sigm(gi) * tanh_f(gg);
            const float h = sigm(go) * tanh_f(cst);
            hwr16(hp, b, u, (_Float16)h);
            if (store_h) {
                const short hh = tb(h);
                const short hl = tb(h - fb((unsigned)(unsigned short)hh));
                *hout = (unsigned)(unsigned short)hh |
                        ((unsigned)(unsigned short)hl << 16);
            }
            if (do_head && t == T_STEPS - 1) hf[b * HID + u] = h;
        } else if (t + 8 < T_STEPS) {
            // step t+8 lands in buf[g&1] (group g+2), row 4s+b
            if (x0) {
                if (t2m < 64) {
                    const int b = t2m >> 4, k = t2m & 15;
                    xwr16(&xp[g & 1][0], s * 4 + b, k, (_Float16)pxn);
                }
            } else {
                const int b = t2m >> 6, u = t2m & 63;
                xwr16(&xp[g & 1][0], s * 4 + b, u,
                      (_Float16)(fb(phn) + fb(phn >> 16)));
            }
        }
        __syncthreads();

        if (s == 3) { CxA = CxnA; CxB = CxnB; }   // group hand-off
        hin += SEQS;
        hout += SEQS;
        if (x0) xin += 16;
    }

    // ---- head: out = h2[T-1] @ Wout^T + bout ----
    if (do_head && tid < 7 * CB) {
        const int b = tid / 7, o = tid % 7;
        float a = bout[o];
        #pragma unroll
        for (int k = 0; k < HID; ++k)
            a = fmaf(hf[b * HID + k], Wout[o * HID + k], a);
        out[(b0 + b) * 7 + o] = a;
    }
}

extern "C" void kernel_launch(void* const* d_in, const int* in_sizes, int n_in,
                              void* d_out, int out_size, void* d_ws, size_t ws_size,
                              hipStream_t stream) {
    const float* x    = (const float*)d_in[0];
    const float* Wih0 = (const float*)d_in[1];
    const float* Whh0 = (const float*)d_in[2];
    const float* bih0 = (const float*)d_in[3];
    const float* bhh0 = (const float*)d_in[4];
    const float* Wih1 = (const float*)d_in[5];
    const float* Whh1 = (const float*)d_in[6];
    const float* bih1 = (const float*)d_in[7];
    const float* bhh1 = (const float*)d_in[8];
    const float* Wih2 = (const float*)d_in[9];
    const float* Whh2 = (const float*)d_in[10];
    const float* bih2 = (const float*)d_in[11];
    const float* bhh2 = (const float*)d_in[12];
    const float* Wout = (const float*)d_in[13];
    const float* bout = (const float*)d_in[14];
    float* out = (float*)d_out;
    unsigned* hseq = (unsigned*)d_ws;   // needs T*B*64*4 = 268,435,456 B

    const dim3 grid(BATCH / CB), blk(NTHR);
    lstm_layer<<<grid, blk, 0, stream>>>(x, hseq, Wih0, Whh0, bih0, bhh0,
                                         nullptr, nullptr, nullptr, 16, 1, 0);
    lstm_layer<<<grid, blk, 0, stream>>>(nullptr, hseq, Wih1, Whh1, bih1, bhh1,
                                         nullptr, nullptr, nullptr, HID, 1, 0);
    lstm_layer<<<grid, blk, 0, stream>>>(nullptr, hseq, Wih2, Whh2, bih2, bhh2,
                                         Wout, bout, out, HID, 0, 1);
}

// Round 15
// 1265.163 us; speedup vs baseline: 1.5377x; 1.0415x over previous
//
#include <hip/hip_runtime.h>
#include <math.h>

// 3-layer LSTM (H=64, T=512, B=2048, Din=16), R15: consolidation.
// Ledger: R11=1288us (best: 1024-thr wave-specialized), R12=1308 (fp16 x-plane
// GOOD, gts [b][u][4] relayout BAD: 8.4M->25.7M bank-conflict cyc), R13=1945
// (half-wave split serializes exec halves), R14=1318 (2 blocks/CU: no overlap
// win). R15 = R11 structure + R12's fp16-x-plane ONLY:
//  - single fp16 x plane (2 MFMA x-pass, half the x staging/reads)
//  - gts in R11's [b][gate*64+u] layout (2-way-conflict writes, free)
//  - strided b32 cell reads (R11's proven path)
// Numerics: fp16 1-term W + fp16 x/h planes, fp32 cell, hseq u32 bf16 hi|lo.
// All global access patterns byte-identical to R11/R12 (determinism proven).

#define T_STEPS 512
#define BATCH   2048
#define HID     64
#define NG      256
#define CB      8
#define NTHR    1024
#define SEQS    (BATCH * HID)     // hseq u32 elements per timestep

typedef __attribute__((ext_vector_type(8))) _Float16 f16x8;
typedef __attribute__((ext_vector_type(4))) float f32x4;

__device__ __forceinline__ float sigm(float z) { return 1.0f / (1.0f + __expf(-z)); }
__device__ __forceinline__ float tanh_f(float z) {
    z = fminf(15.0f, fmaxf(-15.0f, z));
    const float e = __expf(2.0f * z);
    return (e - 1.0f) / (e + 1.0f);
}
// truncate f32 -> bf16 (lo term captures the remainder)
__device__ __forceinline__ short tb(float v) { return (short)(__float_as_uint(v) >> 16); }
__device__ __forceinline__ float fb(unsigned h) {
    return __uint_as_float((h & 0xffffu) << 16);
}
// 8-row 128B/row fp16 plane, XOR-swizzled 16B units; rows alias &7
__device__ __forceinline__ int ha(int row, int u8) {
    row &= 7;
    return row * 128 + ((u8 ^ row) << 4);
}
__device__ __forceinline__ void hwr16(_Float16* p, int row, int u, _Float16 v) {
    *(_Float16*)((char*)p + ha(row, u >> 3) + (u & 7) * 2) = v;
}
__device__ __forceinline__ f16x8 hrd16(const _Float16* p, int row, int u8) {
    return *(const f16x8*)((const char*)p + ha(row, u8));
}
// 16-row fp16 x plane (pair-step even in rows 0-7, odd in 8-15), XOR on row&7
__device__ __forceinline__ int xaddr(int row, int u8) {
    return row * 128 + ((u8 ^ (row & 7)) << 4);
}
__device__ __forceinline__ void xwr16(_Float16* p, int row, int k, _Float16 v) {
    *(_Float16*)((char*)p + xaddr(row, k >> 3) + (k & 7) * 2) = v;
}
__device__ __forceinline__ f16x8 xrd16(const _Float16* p, int row, int u8) {
    return *(const f16x8*)((const char*)p + xaddr(row, u8));
}

#define MFMA16(A, B, C)  __builtin_amdgcn_mfma_f32_16x16x32_f16((A), (B), (C), 0, 0, 0)

// x-side pass over fp16 plane buffer NB -> DST (2 timesteps; bias folded in)
#define X_PASS(DST, NB) do {                                                  \
    DST[0] = biasr; DST[1] = biasr; DST[2] = biasr; DST[3] = biasr;           \
    {                                                                         \
        const f16x8 ax0 = xrd16(&xp[NB][0], arow, 0 + ksub);                  \
        DST = MFMA16(ax0, WIh0, DST);                                         \
    }                                                                         \
    if (Din > 32) {                                                           \
        const f16x8 ax1 = xrd16(&xp[NB][0], arow, 4 + ksub);                  \
        DST = MFMA16(ax1, WIh1, DST);                                         \
    }                                                                         \
} while (0)

__device__ __forceinline__ f16x8 ldw16(const float* p) {
    const float4 a = *(const float4*)p;
    const float4 b = *(const float4*)(p + 4);
    f16x8 w;
    w[0]=(_Float16)a.x; w[1]=(_Float16)a.y; w[2]=(_Float16)a.z; w[3]=(_Float16)a.w;
    w[4]=(_Float16)b.x; w[5]=(_Float16)b.y; w[6]=(_Float16)b.z; w[7]=(_Float16)b.w;
    return w;
}

__global__ __launch_bounds__(NTHR) void lstm_layer(
    const float* __restrict__ x0,    // layer0 input [B][T][16] fp32, or null
    unsigned*    __restrict__ hseq,  // [T][B][64] packed bf16 hi|lo<<16
    const float* __restrict__ Wih,   // [256][Din]
    const float* __restrict__ Whh,   // [256][64]
    const float* __restrict__ bih,   // [256]
    const float* __restrict__ bhh,   // [256]
    const float* __restrict__ Wout,  // [7][64] (head only)
    const float* __restrict__ bout,  // [7]
    float* __restrict__ out,         // [B][7]
    int Din, int store_h, int do_head)
{
    __shared__ __attribute__((aligned(16))) _Float16 xp[2][16 * 64];
    __shared__ __attribute__((aligned(16))) _Float16 hpf[8 * 64];
    __shared__ __attribute__((aligned(16))) float gts[8 * NG];
    __shared__ __attribute__((aligned(16))) float hf[8 * HID];

    const int tid  = threadIdx.x;
    const int lane = tid & 63;
    const int wid  = tid >> 6;          // 0..15: N-tile index
    const int ncol = wid * 16 + (lane & 15);
    const int ksub = (lane >> 4) & 3;   // k-subgroup of 8
    const int arow = lane & 15;
    const int b0   = blockIdx.x * CB;

    // ---- weight fragments: 1-term fp16, resident for the whole kernel ----
    f16x8 WIh0 = {0,0,0,0,0,0,0,0}, WIh1 = {0,0,0,0,0,0,0,0};
    f16x8 WHh0, WHh1;
    {
        const int k0 = ksub * 8;
        if (k0 < Din) WIh0 = ldw16(Wih + ncol * Din + k0);
        if (Din > 32) WIh1 = ldw16(Wih + ncol * Din + 32 + k0);
        WHh0 = ldw16(Whh + ncol * HID + k0);
        WHh1 = ldw16(Whh + ncol * HID + 32 + k0);
    }
    const float biasr = bih[ncol] + bhh[ncol];

    // ---- zero h plane and both x buffers ----
    hpf[tid & 511] = (_Float16)0.f;
    ((unsigned*)xp)[tid] = 0;     // 1024 u32 = 2048 fp16 = both planes
    __syncthreads();

    // ---- prologue: stage steps 0..3 (pairs {0,1}->buf0, {2,3}->buf1) ----
    if (tid >= 512) {
        const int t2 = tid - 512;
        if (x0) {
            if (t2 < 128) {
                const int b = t2 >> 4, k = t2 & 15;
                #pragma unroll
                for (int s = 0; s < 4; ++s) {
                    const float v = x0[(size_t)(b0 + b) * (T_STEPS * 16) + s * 16 + k];
                    xwr16(&xp[(s >> 1) & 1][0], ((s & 1) << 3) + b, k, (_Float16)v);
                }
            }
        } else {
            const int b = t2 >> 6, u = t2 & 63;
            #pragma unroll
            for (int s = 0; s < 4; ++s) {
                const unsigned p = hseq[(size_t)s * SEQS + (b0 + b) * HID + u];
                const float v = fb(p) + fb(p >> 16);
                xwr16(&xp[(s >> 1) & 1][0], ((s & 1) << 3) + b, u, (_Float16)v);
            }
        }
    }
    __syncthreads();

    // ---- prologue: x contribution (+bias) for pair {0,1} ----
    f32x4 CxCur; X_PASS(CxCur, 0);
    f32x4 CxNext = {0.f, 0.f, 0.f, 0.f};

    float cst = 0.0f;   // c state (threads < 512: one (b,u) cell each)

    // running pointers (hoisted addressing) -- identical to R11
    const unsigned* hin = hseq + (size_t)4 * SEQS +
                          (size_t)(b0 + ((tid - 512) >> 6)) * HID + ((tid - 512) & 63);
    const float* xin = x0 ? x0 + (size_t)(b0 + ((tid - 512) >> 4)) * (T_STEPS * 16) +
                             4 * 16 + ((tid - 512) & 15)
                          : nullptr;
    unsigned* hout = hseq + (size_t)(b0 + (tid >> 6)) * HID + (tid & 63);

    for (int t = 0; t < T_STEPS; ++t) {
        // ---- w1: issue x(t+4) prefetch; h-side MFMA folded onto Cx ----
        float pxn = 0.0f; unsigned phn = 0;
        if (tid >= 512 && t + 4 < T_STEPS) {
            if (x0) {
                if (tid - 512 < 128) pxn = *xin;
            } else {
                phn = *hin;
            }
        }

        f32x4 G;
        {
            const f16x8 ah0 = hrd16(hpf, arow, ksub);       // k 0..31
            const f16x8 ah1 = hrd16(hpf, arow, 4 + ksub);   // k 32..63
            G = MFMA16(ah0, WHh0, CxCur);
            G = MFMA16(ah1, WHh1, G);
        }
        // gts writeout (R11 layout): active half-wave, stride-1024B stores
        if ((lane >> 5) == (t & 1)) {
            float* gd = &gts[(((lane >> 4) & 1) * 4) * NG + ncol];
            gd[0]      = G[0];
            gd[NG]     = G[1];
            gd[2 * NG] = G[2];
            gd[3 * NG] = G[3];
        }
        __syncthreads();

        // ---- w2: (even t) x-pass for pair {t+2,t+3} || cell || staging ----
        if ((t & 1) == 0 && t + 2 < T_STEPS) {
            X_PASS(CxNext, ((t >> 1) + 1) & 1);
        }

        if (tid < 512) {
            const int b = tid >> 6, u = tid & 63;
            const float* gsrc = &gts[b * NG + u];
            const float gi = gsrc[0];
            const float gf = gsrc[64];
            const float gg = gsrc[128];
            const float go = gsrc[192];
            cst = sigm(gf) * cst + sigm(gi) * tanh_f(gg);
            const float h = sigm(go) * tanh_f(cst);
            hwr16(hpf, b, u, (_Float16)h);
            if (store_h) {
                const short h_hi = tb(h);
                const short h_lo = tb(h - fb((unsigned)(unsigned short)h_hi));
                *hout = (unsigned)(unsigned short)h_hi |
                        ((unsigned)(unsigned short)h_lo << 16);
            }
            if (do_head && t == T_STEPS - 1) hf[b * HID + u] = h;
        } else if (t + 4 < T_STEPS) {
            const int t2 = tid - 512;
            const int wb = (t >> 1) & 1;            // buffer of pair (t+4)>>1
            const int rsh = (t & 1) << 3;           // row half of step t+4
            if (x0) {
                if (t2 < 128) {
                    const int b = t2 >> 4, k = t2 & 15;
                    xwr16(&xp[wb][0], rsh + b, k, (_Float16)pxn);
                }
            } else {
                const int b = t2 >> 6, u = t2 & 63;
                const float v = fb(phn) + fb(phn >> 16);
                xwr16(&xp[wb][0], rsh + b, u, (_Float16)v);
            }
        }
        __syncthreads();

        if (t & 1) CxCur = CxNext;   // pair hand-off (wave-uniform)
        hin += SEQS;
        if (x0) xin += 16;
        hout += SEQS;
    }

    // ---- head: out = h2[T-1] @ Wout^T + bout ----
    if (do_head && tid < 7 * CB) {
        const int b = tid / 7, o = tid % 7;
        float a = bout[o];
        #pragma unroll
        for (int k = 0; k < HID; ++k)
            a = fmaf(hf[b * HID + k], Wout[o * HID + k], a);
        out[(b0 + b) * 7 + o] = a;
    }
}

extern "C" void kernel_launch(void* const* d_in, const int* in_sizes, int n_in,
                              void* d_out, int out_size, void* d_ws, size_t ws_size,
                              hipStream_t stream) {
    const float* x    = (const float*)d_in[0];
    const float* Wih0 = (const float*)d_in[1];
    const float* Whh0 = (const float*)d_in[2];
    const float* bih0 = (const float*)d_in[3];
    const float* bhh0 = (const float*)d_in[4];
    const float* Wih1 = (const float*)d_in[5];
    const float* Whh1 = (const float*)d_in[6];
    const float* bih1 = (const float*)d_in[7];
    const float* bhh1 = (const float*)d_in[8];
    const float* Wih2 = (const float*)d_in[9];
    const float* Whh2 = (const float*)d_in[10];
    const float* bih2 = (const float*)d_in[11];
    const float* bhh2 = (const float*)d_in[12];
    const float* Wout = (const float*)d_in[13];
    const float* bout = (const float*)d_in[14];
    float* out = (float*)d_out;
    unsigned* hseq = (unsigned*)d_ws;   // needs T*B*64*4 = 268,435,456 B

    const dim3 grid(BATCH / CB), blk(NTHR);
    lstm_layer<<<grid, blk, 0, stream>>>(x, hseq, Wih0, Whh0, bih0, bhh0,
                                         nullptr, nullptr, nullptr, 16, 1, 0);
    lstm_layer<<<grid, blk, 0, stream>>>(nullptr, hseq, Wih1, Whh1, bih1, bhh1,
                                         nullptr, nullptr, nullptr, HID, 1, 0);
    lstm_layer<<<grid, blk, 0, stream>>>(nullptr, hseq, Wih2, Whh2, bih2, bhh2,
                                         Wout, bout, out, HID, 0, 1);
}